// Round 4
// baseline (1943.244 us; speedup 1.0000x reference)
//
#include <hip/hip_runtime.h>
#include <stdint.h>

#define NV 163842
#define EPSV 1e-5f

using short8 = __attribute__((ext_vector_type(8))) short;   // 8 bf16 (4 VGPRs)
using f32x4  = __attribute__((ext_vector_type(4))) float;   // MFMA acc

static __device__ __forceinline__ unsigned short f2bf(float f) {
    union { float f; unsigned int i; } v; v.f = f;
    return (unsigned short)((v.i + 0x7FFFu + ((v.i >> 16) & 1u)) >> 16);  // RNE
}
static __device__ __forceinline__ void bf2x(unsigned int w, float& a, float& b) {
    union { unsigned int i; float f; } lo, hi;
    lo.i = w << 16; hi.i = w & 0xFFFF0000u;
    a = lo.f; b = hi.f;
}
// pack two fp32 -> bf16x2 (round-half-up) via v_perm byte select
static __device__ __forceinline__ unsigned int pack2(float a, float b) {
    union { float f; unsigned int i; } ua, ub; ua.f = a; ub.f = b;
    return __builtin_amdgcn_perm(ub.i + 0x8000u, ua.i + 0x8000u, 0x07060302);
}

// ---- zero the stats accumulator ----
__global__ __launch_bounds__(256) void k_zero(float* __restrict__ ACC) {
    ACC[threadIdx.x] = 0.f;
    ACC[256 + threadIdx.x] = 0.f;
}

// ---- cast x fp32->bf16 into C cols [0,64); accumulate per-channel sum/sumsq ----
__global__ __launch_bounds__(256) void k_cast(const float* __restrict__ x,
                                              unsigned short* __restrict__ C,
                                              float* __restrict__ ACC) {
    const int t = threadIdx.x;
    const int wv = t >> 6, lane = t & 63;
    const int v = blockIdx.x * 64 + (t >> 2);
    const int c0 = (t & 3) * 16;
    float f[16];
    const bool valid = v < NV;
    if (valid) {
        const float4* p = (const float4*)(x + (size_t)v * 64 + c0);
#pragma unroll
        for (int i = 0; i < 4; ++i) {
            float4 q = p[i];
            f[i * 4 + 0] = q.x; f[i * 4 + 1] = q.y; f[i * 4 + 2] = q.z; f[i * 4 + 3] = q.w;
        }
        unsigned int o[8];
#pragma unroll
        for (int i = 0; i < 8; ++i)
            o[i] = ((unsigned int)f2bf(f[2 * i])) | (((unsigned int)f2bf(f[2 * i + 1])) << 16);
        uint4* dst = (uint4*)(C + (size_t)v * 256 + c0);
        dst[0] = uint4{o[0], o[1], o[2], o[3]};
        dst[1] = uint4{o[4], o[5], o[6], o[7]};
    } else {
#pragma unroll
        for (int i = 0; i < 16; ++i) f[i] = 0.f;
    }
    float s[16], s2[16];
#pragma unroll
    for (int i = 0; i < 16; ++i) { s[i] = f[i]; s2[i] = f[i] * f[i]; }
#pragma unroll
    for (int mask = 4; mask <= 32; mask <<= 1) {
#pragma unroll
        for (int i = 0; i < 16; ++i) {
            s[i]  += __shfl_xor(s[i],  mask);
            s2[i] += __shfl_xor(s2[i], mask);
        }
    }
    __shared__ float red[4 * 128];
    if ((lane >> 2) == 0) {
        int cb = (lane & 3) * 16;
#pragma unroll
        for (int i = 0; i < 16; ++i) {
            red[wv * 128 + cb + i]      = s[i];
            red[wv * 128 + 64 + cb + i] = s2[i];
        }
    }
    __syncthreads();
    if (t < 128) {
        float v4 = red[t] + red[128 + t] + red[256 + t] + red[384 + t];
        int c = t & 63, which = t >> 6;
        atomicAdd(&ACC[which * 256 + c], v4);
    }
}

// ---- transpose all four W [7cin,64] fp32 -> WT [64,7cin] bf16 ----
__global__ __launch_bounds__(256) void k_wt_all(const float* __restrict__ W1,
                                                const float* __restrict__ W2,
                                                const float* __restrict__ W3,
                                                const float* __restrict__ W4,
                                                unsigned short* __restrict__ WT) {
    int j = blockIdx.x * 256 + threadIdx.x;
    if (j >= 286720) return;
    const float* W; int jj, K7;
    if (j < 28672)       { W = W1; jj = j;          K7 = 448;  }
    else if (j < 86016)  { W = W2; jj = j - 28672;  K7 = 896;  }
    else if (j < 172032) { W = W3; jj = j - 86016;  K7 = 1344; }
    else                 { W = W4; jj = j - 172032; K7 = 1792; }
    int n = jj / K7, k = jj - n * K7;
    WT[j] = f2bf(W[(size_t)k * 64 + n]);
}

// ---- fused gather + BN/lrelu (in-register) + GEMM + stats ----
template<int CIN, int GRP, bool FINAL>
__global__ __launch_bounds__(256, 4) void k_gg(const unsigned short* __restrict__ C,
                                               const int* __restrict__ neigh,
                                               const unsigned short* __restrict__ WT,
                                               const float* __restrict__ g,
                                               const float* __restrict__ bglob,
                                               const float* __restrict__ wb,
                                               float* __restrict__ ACC,
                                               unsigned short* __restrict__ Cout,
                                               float* __restrict__ Fout) {
    constexpr int KB2  = CIN / 32;      // 32-k chunks per neighbor row
    constexpr int NC   = 7 * KB2;       // total chunks (14/28/42/56)
    constexpr int K7   = 7 * CIN;
    constexpr int NSEG = K7 / 224;      // 224-k segments (2/4/6/8)

    __shared__ unsigned int sBN[256];          // pack2(scale, shift) per channel, bf16x2
    __shared__ int sIdx[896];
    __shared__ unsigned short sW[64 * 232];    // 224 + 8 pad per row

    const int t = threadIdx.x;
    const int v0 = blockIdx.x * 128;

    if (t < CIN) {   // fold stats + g/b into per-channel scale/shift
        float s = ACC[t], s2 = ACC[256 + t];
        float mu = s * (1.0f / NV);
        float var = fmaf(-mu, mu, s2 * (1.0f / NV));
        float sc = g[t] * rsqrtf(var + EPSV);
        float sh = bglob[t] - mu * sc;
        sBN[t] = pack2(sc, sh);
    }
    for (int q = t; q < 896; q += 256) {
        int gi = v0 * 7 + q;
        sIdx[q] = (gi < NV * 7) ? neigh[gi] : 0;
    }
    __syncthreads();

    const int wv = t >> 6, lane = t & 63;
    const int m = lane & 15, quad = lane >> 4;

    // byte offsets into C for this lane's two gather rows, per neighbor slot
    unsigned int voff0[7], voff1[7];
#pragma unroll
    for (int r = 0; r < 7; ++r) {
        voff0[r] = (unsigned)sIdx[(wv * 32 + m) * 7 + r] * 512u + (unsigned)quad * 16u;
        voff1[r] = (unsigned)sIdx[(wv * 32 + 16 + m) * 7 + r] * 512u + (unsigned)quad * 16u;
    }
    const char* Cb = (const char*)C;

    f32x4 acc[2][4];
#pragma unroll
    for (int i = 0; i < 2; ++i)
#pragma unroll
        for (int j = 0; j < 4; ++j) acc[i][j] = f32x4{0.f, 0.f, 0.f, 0.f};

    auto loadRaw = [&](int c, uint4& p0, uint4& p1) {
        int r = c / KB2, kc = c % KB2;
        p0 = *(const uint4*)(Cb + voff0[r] + kc * 64);
        p1 = *(const uint4*)(Cb + voff1[r] + kc * 64);
    };
    // BN + lrelu + repack one raw 16-elem pair into MFMA A-frags
    auto bnA = [&](const uint4& p0, const uint4& p1, int c, short8& A0, short8& A1) {
        int kc = c % KB2;
        int chb = kc * 32 + quad * 8;
        uint4 q0 = *(const uint4*)&sBN[chb];
        uint4 q1 = *(const uint4*)&sBN[chb + 4];
        float sc[8], sh[8];
        bf2x(q0.x, sc[0], sh[0]); bf2x(q0.y, sc[1], sh[1]);
        bf2x(q0.z, sc[2], sh[2]); bf2x(q0.w, sc[3], sh[3]);
        bf2x(q1.x, sc[4], sh[4]); bf2x(q1.y, sc[5], sh[5]);
        bf2x(q1.z, sc[6], sh[6]); bf2x(q1.w, sc[7], sh[7]);
        unsigned int u0[4] = {p0.x, p0.y, p0.z, p0.w};
        unsigned int u1[4] = {p1.x, p1.y, p1.z, p1.w};
        unsigned int o0[4], o1[4];
#pragma unroll
        for (int d = 0; d < 4; ++d) {
            float a, b, y0, y1;
            bf2x(u0[d], a, b);
            y0 = fmaf(a, sc[2 * d], sh[2 * d]);     y0 = fmaxf(y0, 0.2f * y0);
            y1 = fmaf(b, sc[2 * d + 1], sh[2 * d + 1]); y1 = fmaxf(y1, 0.2f * y1);
            o0[d] = pack2(y0, y1);
            bf2x(u1[d], a, b);
            y0 = fmaf(a, sc[2 * d], sh[2 * d]);     y0 = fmaxf(y0, 0.2f * y0);
            y1 = fmaf(b, sc[2 * d + 1], sh[2 * d + 1]); y1 = fmaxf(y1, 0.2f * y1);
            o1[d] = pack2(y0, y1);
        }
        union { uint4 u; short8 s; } c0, c1;
        c0.u = uint4{o0[0], o0[1], o0[2], o0[3]};
        c1.u = uint4{o1[0], o1[1], o1[2], o1[3]};
        A0 = c0.s; A1 = c1.s;
    };

    uint4 pa0[3], pa1[3], qa0[3], qa1[3];   // dual-bank 3-deep prefetch

    // one segment: stage B, prime next bank, run 7 chunks off cur bank
    auto run_seg = [&](int seg, uint4 (&ca0)[3], uint4 (&ca1)[3],
                       uint4 (&na0)[3], uint4 (&na1)[3]) {
        __syncthreads();   // sW safe to overwrite
        {   // stage 224-k W segment
            const int n = t >> 2, qq = t & 3;
            const unsigned short* src = WT + (size_t)n * K7 + seg * 224 + qq * 56;
            unsigned short* dst = sW + n * 232 + qq * 56;
#pragma unroll
            for (int p = 0; p < 7; ++p)
                *(uint4*)(dst + p * 8) = *(const uint4*)(src + p * 8);
        }
        if (seg + 1 < NSEG) {   // prime next segment's first 3 chunks (latency rides the barrier)
#pragma unroll
            for (int d = 0; d < 3; ++d)
                loadRaw((seg + 1) * 7 + d, na0[d], na1[d]);
        }
        __syncthreads();
#pragma unroll
        for (int cc = 0; cc < 7; ++cc) {
            const int c = seg * 7 + cc;
            short8 A0, A1;
            bnA(ca0[cc % 3], ca1[cc % 3], c, A0, A1);
            if (cc < 4) loadRaw(c + 3, ca0[cc % 3], ca1[cc % 3]);   // within-segment refill
#pragma unroll
            for (int ct = 0; ct < 4; ++ct) {
                short8 bf = *(const short8*)(sW + (ct * 16 + m) * 232 + cc * 32 + quad * 8);
                acc[0][ct] = __builtin_amdgcn_mfma_f32_16x16x32_bf16(A0, bf, acc[0][ct], 0, 0, 0);
                acc[1][ct] = __builtin_amdgcn_mfma_f32_16x16x32_bf16(A1, bf, acc[1][ct], 0, 0, 0);
            }
        }
    };

#pragma unroll
    for (int d = 0; d < 3; ++d) loadRaw(d, pa0[d], pa1[d]);   // prime bank 0
    for (int seg = 0; seg < NSEG; ++seg) {
        if (seg & 1) run_seg(seg, qa0, qa1, pa0, pa1);
        else         run_seg(seg, pa0, pa1, qa0, qa1);
    }

    // epilogue: bias, write, per-channel stats for the produced 64-col group
    __syncthreads();   // sW dead; reuse as reduction scratch
    float bsum[4]  = {0.f, 0.f, 0.f, 0.f};
    float b2sum[4] = {0.f, 0.f, 0.f, 0.f};
#pragma unroll
    for (int mt = 0; mt < 2; ++mt) {
#pragma unroll
        for (int ct = 0; ct < 4; ++ct) {
            int col = ct * 16 + m;
            float bv = wb[col];
#pragma unroll
            for (int j = 0; j < 4; ++j) {
                int vr = v0 + wv * 32 + mt * 16 + quad * 4 + j;
                float val = acc[mt][ct][j] + bv;
                if (vr < NV) {
                    if (FINAL) {
                        Fout[(size_t)vr * 64 + col] = val;
                    } else {
                        Cout[(size_t)vr * 256 + GRP * 64 + col] = f2bf(val);
                        bsum[ct] += val; b2sum[ct] += val * val;
                    }
                }
            }
        }
    }
    if (!FINAL) {
#pragma unroll
        for (int ct = 0; ct < 4; ++ct) {   // reduce over quads
            bsum[ct]  += __shfl_xor(bsum[ct], 16);
            bsum[ct]  += __shfl_xor(bsum[ct], 32);
            b2sum[ct] += __shfl_xor(b2sum[ct], 16);
            b2sum[ct] += __shfl_xor(b2sum[ct], 32);
        }
        float* red = (float*)sW;
        if (quad == 0) {
#pragma unroll
            for (int ct = 0; ct < 4; ++ct) {
                red[wv * 128 + ct * 16 + m]       = bsum[ct];
                red[512 + wv * 128 + ct * 16 + m] = b2sum[ct];
            }
        }
        __syncthreads();
        if (t < 128) {
            int c = t & 63, which = t >> 6;
            float s = red[which * 512 + c] + red[which * 512 + 128 + c] +
                      red[which * 512 + 256 + c] + red[which * 512 + 384 + c];
            atomicAdd(&ACC[which * 256 + GRP * 64 + c], s);
        }
    }
}

extern "C" void kernel_launch(void* const* d_in, const int* in_sizes, int n_in,
                              void* d_out, int out_size, void* d_ws, size_t ws_size,
                              hipStream_t stream) {
    const float* x     = (const float*)d_in[0];
    const int*   neigh = (const int*)d_in[1];
    const float* G[4]  = {(const float*)d_in[2],  (const float*)d_in[6],
                          (const float*)d_in[10], (const float*)d_in[14]};
    const float* B[4]  = {(const float*)d_in[3],  (const float*)d_in[7],
                          (const float*)d_in[11], (const float*)d_in[15]};
    const float* W[4]  = {(const float*)d_in[4],  (const float*)d_in[8],
                          (const float*)d_in[12], (const float*)d_in[16]};
    const float* WB[4] = {(const float*)d_in[5],  (const float*)d_in[9],
                          (const float*)d_in[13], (const float*)d_in[17]};
    float* out = (float*)d_out;

    char* ws = (char*)d_ws;
    size_t off = 0;
    unsigned short* C  = (unsigned short*)(ws + off); off += (size_t)NV * 256 * 2;  // raw concat x|x1|x2|x3 (bf16)
    unsigned short* WT = (unsigned short*)(ws + off); off += (size_t)286720 * 2;    // transposed bf16 W (all 4)
    float* ACC         = (float*)(ws + off);          off += 512 * 4;               // sum[256], sumsq[256]

    k_zero<<<1, 256, 0, stream>>>(ACC);
    k_cast<<<(NV + 63) / 64, 256, 0, stream>>>(x, C, ACC);
    k_wt_all<<<(286720 + 255) / 256, 256, 0, stream>>>(W[0], W[1], W[2], W[3], WT);

    const int GG = (NV + 127) / 128;
    k_gg< 64, 1, false><<<GG, 256, 0, stream>>>(C, neigh, WT,          G[0], B[0], WB[0], ACC, C, nullptr);
    k_gg<128, 2, false><<<GG, 256, 0, stream>>>(C, neigh, WT + 28672,  G[1], B[1], WB[1], ACC, C, nullptr);
    k_gg<192, 3, false><<<GG, 256, 0, stream>>>(C, neigh, WT + 86016,  G[2], B[2], WB[2], ACC, C, nullptr);
    k_gg<256, 0, true ><<<GG, 256, 0, stream>>>(C, neigh, WT + 172032, G[3], B[3], WB[3], ACC, nullptr, out);
}

// Round 5
// 619.805 us; speedup vs baseline: 3.1353x; 3.1353x over previous
//
#include <hip/hip_runtime.h>
#include <stdint.h>

#define NV 163842
#define EPSV 1e-5f

using short8 = __attribute__((ext_vector_type(8))) short;   // 8 bf16 (4 VGPRs)
using f32x4  = __attribute__((ext_vector_type(4))) float;   // MFMA acc

static __device__ __forceinline__ unsigned short f2bf(float f) {
    union { float f; unsigned int i; } v; v.f = f;
    return (unsigned short)((v.i + 0x7FFFu + ((v.i >> 16) & 1u)) >> 16);  // RNE
}
static __device__ __forceinline__ void bf2x(unsigned int w, float& a, float& b) {
    union { unsigned int i; float f; } lo, hi;
    lo.i = w << 16; hi.i = w & 0xFFFF0000u;
    a = lo.f; b = hi.f;
}
// pack two fp32 -> bf16x2 (round-half-up) via v_perm byte select
static __device__ __forceinline__ unsigned int pack2(float a, float b) {
    union { float f; unsigned int i; } ua, ub; ua.f = a; ub.f = b;
    return __builtin_amdgcn_perm(ub.i + 0x8000u, ua.i + 0x8000u, 0x07060302);
}

// ---- zero the stats accumulator ----
__global__ __launch_bounds__(256) void k_zero(float* __restrict__ ACC) {
    ACC[threadIdx.x] = 0.f;
    ACC[256 + threadIdx.x] = 0.f;
}

// ---- cast x fp32->bf16 into C cols [0,64); accumulate per-channel sum/sumsq ----
__global__ __launch_bounds__(256) void k_cast(const float* __restrict__ x,
                                              unsigned short* __restrict__ C,
                                              float* __restrict__ ACC) {
    const int t = threadIdx.x;
    const int wv = t >> 6, lane = t & 63;
    const int v = blockIdx.x * 64 + (t >> 2);
    const int c0 = (t & 3) * 16;
    float f[16];
    const bool valid = v < NV;
    if (valid) {
        const float4* p = (const float4*)(x + (size_t)v * 64 + c0);
#pragma unroll
        for (int i = 0; i < 4; ++i) {
            float4 q = p[i];
            f[i * 4 + 0] = q.x; f[i * 4 + 1] = q.y; f[i * 4 + 2] = q.z; f[i * 4 + 3] = q.w;
        }
        unsigned int o[8];
#pragma unroll
        for (int i = 0; i < 8; ++i)
            o[i] = ((unsigned int)f2bf(f[2 * i])) | (((unsigned int)f2bf(f[2 * i + 1])) << 16);
        uint4* dst = (uint4*)(C + (size_t)v * 256 + c0);
        dst[0] = uint4{o[0], o[1], o[2], o[3]};
        dst[1] = uint4{o[4], o[5], o[6], o[7]};
    } else {
#pragma unroll
        for (int i = 0; i < 16; ++i) f[i] = 0.f;
    }
    float s[16], s2[16];
#pragma unroll
    for (int i = 0; i < 16; ++i) { s[i] = f[i]; s2[i] = f[i] * f[i]; }
#pragma unroll
    for (int mask = 4; mask <= 32; mask <<= 1) {
#pragma unroll
        for (int i = 0; i < 16; ++i) {
            s[i]  += __shfl_xor(s[i],  mask);
            s2[i] += __shfl_xor(s2[i], mask);
        }
    }
    __shared__ float red[4 * 128];
    if ((lane >> 2) == 0) {
        int cb = (lane & 3) * 16;
#pragma unroll
        for (int i = 0; i < 16; ++i) {
            red[wv * 128 + cb + i]      = s[i];
            red[wv * 128 + 64 + cb + i] = s2[i];
        }
    }
    __syncthreads();
    if (t < 128) {
        float v4 = red[t] + red[128 + t] + red[256 + t] + red[384 + t];
        int c = t & 63, which = t >> 6;
        atomicAdd(&ACC[which * 256 + c], v4);
    }
}

// ---- transpose all four W [7cin,64] fp32 -> WT [64,7cin] bf16 ----
__global__ __launch_bounds__(256) void k_wt_all(const float* __restrict__ W1,
                                                const float* __restrict__ W2,
                                                const float* __restrict__ W3,
                                                const float* __restrict__ W4,
                                                unsigned short* __restrict__ WT) {
    int j = blockIdx.x * 256 + threadIdx.x;
    if (j >= 286720) return;
    const float* W; int jj, K7;
    if (j < 28672)       { W = W1; jj = j;          K7 = 448;  }
    else if (j < 86016)  { W = W2; jj = j - 28672;  K7 = 896;  }
    else if (j < 172032) { W = W3; jj = j - 86016;  K7 = 1344; }
    else                 { W = W4; jj = j - 172032; K7 = 1792; }
    int n = jj / K7, k = jj - n * K7;
    WT[j] = f2bf(W[(size_t)k * 64 + n]);
}

// ---- stage 1: dense BN+lrelu GEMM  Z[v, (r-r0)*64+n] = y[v,:] @ W[r-block] ----
// A-frags direct global->VGPR (each element read exactly once), B per group in LDS.
template<int CIN>
__global__ __launch_bounds__(512, 4) void k_lin(const unsigned short* __restrict__ C,
                                                const unsigned short* __restrict__ WT,
                                                const float* __restrict__ g,
                                                const float* __restrict__ bglob,
                                                const float* __restrict__ ACC,
                                                unsigned short* __restrict__ Z,
                                                int ZW, int r0, int r1) {
    constexpr int K7 = 7 * CIN;
    constexpr int KC = CIN / 32;       // 32-k chunks
    constexpr int LW = CIN + 8;        // sW row stride (pad)
    constexpr int C8 = CIN / 8;        // uint4 per B row
    __shared__ unsigned int sBN[CIN];
    __shared__ unsigned short sW[64 * LW];

    const int t = threadIdx.x;
    if (t < CIN) {   // fold stats + g/b into packed bf16 (scale, shift)
        float s = ACC[t], s2 = ACC[256 + t];
        float mu = s * (1.0f / NV);
        float var = fmaf(-mu, mu, s2 * (1.0f / NV));
        float sc = g[t] * rsqrtf(var + EPSV);
        sBN[t] = pack2(sc, bglob[t] - mu * sc);
    }
    const int wv = t >> 6, lane = t & 63, m = lane & 15, quad = lane >> 4;
    int vA = blockIdx.x * 128 + wv * 16 + m;
    if (vA >= NV) vA = NV - 1;                       // clamp; stores guarded
    const unsigned short* Arow = C + (size_t)vA * 256 + quad * 8;

    uint4 raw[KC];
#pragma unroll
    for (int kc = 0; kc < KC; ++kc) raw[kc] = *(const uint4*)(Arow + kc * 32);
    __syncthreads();   // sBN visible (raw loads in flight meanwhile)

    short8 afr[KC];    // BN+lrelu'd A fragments, applied ONCE, live across all groups
#pragma unroll
    for (int kc = 0; kc < KC; ++kc) {
        int chb = kc * 32 + quad * 8;
        uint4 q0 = *(const uint4*)&sBN[chb];
        uint4 q1 = *(const uint4*)&sBN[chb + 4];
        unsigned int qs[8] = {q0.x, q0.y, q0.z, q0.w, q1.x, q1.y, q1.z, q1.w};
        unsigned int u[4]  = {raw[kc].x, raw[kc].y, raw[kc].z, raw[kc].w};
        unsigned int o[4];
#pragma unroll
        for (int d = 0; d < 4; ++d) {
            float sc0, sh0, sc1, sh1, a, b;
            bf2x(qs[2 * d], sc0, sh0);
            bf2x(qs[2 * d + 1], sc1, sh1);
            bf2x(u[d], a, b);
            float y0 = fmaf(a, sc0, sh0); y0 = fmaxf(y0, 0.2f * y0);
            float y1 = fmaf(b, sc1, sh1); y1 = fmaxf(y1, 0.2f * y1);
            o[d] = pack2(y0, y1);
        }
        union { uint4 uu; short8 ss; } cv;
        cv.uu = uint4{o[0], o[1], o[2], o[3]};
        afr[kc] = cv.ss;
    }

    const int vOutB = blockIdx.x * 128 + wv * 16 + quad * 4;
    for (int r = r0; r < r1; ++r) {
        for (int e = t; e < 64 * C8; e += 512) {    // stage B group r
            int n = e / C8, k8 = e - n * C8;
            *(uint4*)(sW + n * LW + k8 * 8) =
                *(const uint4*)(WT + (size_t)n * K7 + r * CIN + k8 * 8);
        }
        __syncthreads();
        f32x4 acc[4];
#pragma unroll
        for (int i = 0; i < 4; ++i) acc[i] = f32x4{0.f, 0.f, 0.f, 0.f};
#pragma unroll
        for (int kc = 0; kc < KC; ++kc) {
#pragma unroll
            for (int ct = 0; ct < 4; ++ct) {
                short8 bf = *(const short8*)(sW + (ct * 16 + m) * LW + kc * 32 + quad * 8);
                acc[ct] = __builtin_amdgcn_mfma_f32_16x16x32_bf16(afr[kc], bf, acc[ct], 0, 0, 0);
            }
        }
        unsigned short* zr = Z + (size_t)(r - r0) * 64;
#pragma unroll
        for (int ct = 0; ct < 4; ++ct)
#pragma unroll
            for (int j = 0; j < 4; ++j) {
                int v = vOutB + j;
                if (v < NV) zr[(size_t)v * ZW + ct * 16 + m] = f2bf(acc[ct][j]);
            }
        __syncthreads();   // protect sW before next group restage
    }
}

// ---- stage 2: gather-sum 7 (or partial) 128-B Z slices + bias -> C group / out, + stats ----
template<int R0, int R1, bool FINAL, bool RDP, bool WRP>
__global__ __launch_bounds__(512) void k_gath(const unsigned short* __restrict__ Z, int ZW,
                                              const int* __restrict__ neigh,
                                              const float* __restrict__ wb,
                                              float* __restrict__ ACC,
                                              unsigned short* __restrict__ CoutG,
                                              float* __restrict__ Fout,
                                              float* __restrict__ PART,
                                              int GRP) {
    __shared__ int sIdx[448];
    __shared__ float red[1024];
    const int t = threadIdx.x;
    const int v0 = blockIdx.x * 64;
    for (int q = t; q < 448; q += 512) {
        int gi = v0 * 7 + q;
        sIdx[q] = (gi < NV * 7) ? neigh[gi] : 0;
    }
    __syncthreads();
    const int vloc = t >> 3, c8 = t & 7;
    const int v = v0 + vloc;
    const bool ok = v < NV;

    float a[8];
    if (RDP) {
        float4 p0{0, 0, 0, 0}, p1{0, 0, 0, 0};
        if (ok) {
            p0 = *(const float4*)(PART + (size_t)v * 64 + c8 * 8);
            p1 = *(const float4*)(PART + (size_t)v * 64 + c8 * 8 + 4);
        }
        a[0] = p0.x; a[1] = p0.y; a[2] = p0.z; a[3] = p0.w;
        a[4] = p1.x; a[5] = p1.y; a[6] = p1.z; a[7] = p1.w;
    } else {
#pragma unroll
        for (int i = 0; i < 8; ++i) a[i] = 0.f;
    }

    uint4 zr[R1 - R0];
#pragma unroll
    for (int r = R0; r < R1; ++r) {   // all loads independent & in flight together
        int u = sIdx[vloc * 7 + r];
        zr[r - R0] = *(const uint4*)(Z + (size_t)u * ZW + (size_t)(r - R0) * 64 + c8 * 8);
    }
#pragma unroll
    for (int r = 0; r < R1 - R0; ++r) {
        float x0, x1;
        bf2x(zr[r].x, x0, x1); a[0] += x0; a[1] += x1;
        bf2x(zr[r].y, x0, x1); a[2] += x0; a[3] += x1;
        bf2x(zr[r].z, x0, x1); a[4] += x0; a[5] += x1;
        bf2x(zr[r].w, x0, x1); a[6] += x0; a[7] += x1;
    }

    if (WRP) {   // first half of split schedule: write partial fp32, no bias/stats yet
        if (ok) {
            *(float4*)(PART + (size_t)v * 64 + c8 * 8)     = float4{a[0], a[1], a[2], a[3]};
            *(float4*)(PART + (size_t)v * 64 + c8 * 8 + 4) = float4{a[4], a[5], a[6], a[7]};
        }
        return;
    }
#pragma unroll
    for (int i = 0; i < 8; ++i) a[i] += wb[c8 * 8 + i];

    if (FINAL) {
        if (ok) {
            *(float4*)(Fout + (size_t)v * 64 + c8 * 8)     = float4{a[0], a[1], a[2], a[3]};
            *(float4*)(Fout + (size_t)v * 64 + c8 * 8 + 4) = float4{a[4], a[5], a[6], a[7]};
        }
        return;
    }
    // bf16 store into concat group + per-channel stats
    unsigned int o[4];
#pragma unroll
    for (int i = 0; i < 4; ++i) o[i] = pack2(a[2 * i], a[2 * i + 1]);
    if (ok) *(uint4*)(CoutG + (size_t)v * 256 + c8 * 8) = uint4{o[0], o[1], o[2], o[3]};

    float s[8], s2[8];
#pragma unroll
    for (int i = 0; i < 8; ++i) {
        float vv = ok ? a[i] : 0.f;
        s[i] = vv; s2[i] = vv * vv;
    }
#pragma unroll
    for (int mask = 8; mask <= 32; mask <<= 1) {
#pragma unroll
        for (int i = 0; i < 8; ++i) {
            s[i]  += __shfl_xor(s[i],  mask);
            s2[i] += __shfl_xor(s2[i], mask);
        }
    }
    const int wv = t >> 6, lane = t & 63;
    if ((lane >> 3) == 0) {
#pragma unroll
        for (int i = 0; i < 8; ++i) {
            red[wv * 64 + c8 * 8 + i]       = s[i];
            red[512 + wv * 64 + c8 * 8 + i] = s2[i];
        }
    }
    __syncthreads();
    if (t < 64) {
        float ss = 0.f, ss2 = 0.f;
#pragma unroll
        for (int w = 0; w < 8; ++w) {
            ss  += red[w * 64 + t];
            ss2 += red[512 + w * 64 + t];
        }
        atomicAdd(&ACC[GRP * 64 + t], ss);
        atomicAdd(&ACC[256 + GRP * 64 + t], ss2);
    }
}

extern "C" void kernel_launch(void* const* d_in, const int* in_sizes, int n_in,
                              void* d_out, int out_size, void* d_ws, size_t ws_size,
                              hipStream_t stream) {
    const float* x     = (const float*)d_in[0];
    const int*   neigh = (const int*)d_in[1];
    const float* G[4]  = {(const float*)d_in[2],  (const float*)d_in[6],
                          (const float*)d_in[10], (const float*)d_in[14]};
    const float* B[4]  = {(const float*)d_in[3],  (const float*)d_in[7],
                          (const float*)d_in[11], (const float*)d_in[15]};
    const float* W[4]  = {(const float*)d_in[4],  (const float*)d_in[8],
                          (const float*)d_in[12], (const float*)d_in[16]};
    const float* WB[4] = {(const float*)d_in[5],  (const float*)d_in[9],
                          (const float*)d_in[13], (const float*)d_in[17]};
    float* out = (float*)d_out;

    char* ws = (char*)d_ws;
    size_t off = 0;
    unsigned short* C  = (unsigned short*)(ws + off); off += (size_t)NV * 256 * 2;
    unsigned short* WT = (unsigned short*)(ws + off); off += (size_t)286720 * 2;
    float* ACC         = (float*)(ws + off);          off += 512 * 4;
    unsigned short* Z  = (unsigned short*)(ws + off);
    const size_t zFull = (size_t)NV * 448 * 2;
    const bool full = ws_size >= off + zFull;        // else: Z halves + partials in d_out

    k_zero<<<1, 256, 0, stream>>>(ACC);
    k_cast<<<(NV + 63) / 64, 256, 0, stream>>>(x, C, ACC);
    k_wt_all<<<(286720 + 255) / 256, 256, 0, stream>>>(W[0], W[1], W[2], W[3], WT);

    const int GL = (NV + 127) / 128;   // k_lin grid
    const int GH = (NV + 63) / 64;     // k_gath grid
    const int WOFF[4] = {0, 28672, 86016, 172032};

    if (full) {
#define LAYER(CIN, LI, GRP)                                                              \
        k_lin<CIN><<<GL, 512, 0, stream>>>(C, WT + WOFF[LI], G[LI], B[LI], ACC, Z, 448, 0, 7); \
        k_gath<0, 7, false, false, false><<<GH, 512, 0, stream>>>(                       \
            Z, 448, neigh, WB[LI], ACC, C + GRP * 64, nullptr, nullptr, GRP)
        LAYER(64, 0, 1);
        LAYER(128, 1, 2);
        LAYER(192, 2, 3);
#undef LAYER
        k_lin<256><<<GL, 512, 0, stream>>>(C, WT + WOFF[3], G[3], B[3], ACC, Z, 448, 0, 7);
        k_gath<0, 7, true, false, false><<<GH, 512, 0, stream>>>(
            Z, 448, neigh, WB[3], ACC, nullptr, out, nullptr, 0);
    } else {
#define LAYER(CIN, LI, GRP)                                                              \
        k_lin<CIN><<<GL, 512, 0, stream>>>(C, WT + WOFF[LI], G[LI], B[LI], ACC, Z, 256, 0, 4); \
        k_gath<0, 4, false, false, true><<<GH, 512, 0, stream>>>(                        \
            Z, 256, neigh, WB[LI], ACC, nullptr, nullptr, out, GRP);                     \
        k_lin<CIN><<<GL, 512, 0, stream>>>(C, WT + WOFF[LI], G[LI], B[LI], ACC, Z, 192, 4, 7); \
        k_gath<4, 7, false, true, false><<<GH, 512, 0, stream>>>(                        \
            Z, 192, neigh, WB[LI], ACC, C + GRP * 64, nullptr, out, GRP)
        LAYER(64, 0, 1);
        LAYER(128, 1, 2);
        LAYER(192, 2, 3);
#undef LAYER
        k_lin<256><<<GL, 512, 0, stream>>>(C, WT + WOFF[3], G[3], B[3], ACC, Z, 256, 0, 4);
        k_gath<0, 4, false, false, true><<<GH, 512, 0, stream>>>(
            Z, 256, neigh, WB[3], ACC, nullptr, nullptr, out, 0);
        k_lin<256><<<GL, 512, 0, stream>>>(C, WT + WOFF[3], G[3], B[3], ACC, Z, 192, 4, 7);
        k_gath<4, 7, true, true, false><<<GH, 512, 0, stream>>>(
            Z, 192, neigh, WB[3], ACC, nullptr, out, out, 0);
    }
}

// Round 6
// 551.438 us; speedup vs baseline: 3.5240x; 1.1240x over previous
//
#include <hip/hip_runtime.h>
#include <stdint.h>

#define NV 163842
#define EPSV 1e-5f

using short8 = __attribute__((ext_vector_type(8))) short;   // 8 bf16 (4 VGPRs)
using f32x4  = __attribute__((ext_vector_type(4))) float;   // MFMA acc

static __device__ __forceinline__ unsigned short f2bf(float f) {
    union { float f; unsigned int i; } v; v.f = f;
    return (unsigned short)((v.i + 0x7FFFu + ((v.i >> 16) & 1u)) >> 16);  // RNE
}
static __device__ __forceinline__ void bf2x(unsigned int w, float& a, float& b) {
    union { unsigned int i; float f; } lo, hi;
    lo.i = w << 16; hi.i = w & 0xFFFF0000u;
    a = lo.f; b = hi.f;
}
// pack two fp32 -> bf16x2 (round-half-up) via v_perm byte select
static __device__ __forceinline__ unsigned int pack2(float a, float b) {
    union { float f; unsigned int i; } ua, ub; ua.f = a; ub.f = b;
    return __builtin_amdgcn_perm(ub.i + 0x8000u, ua.i + 0x8000u, 0x07060302);
}

// ---- zero the stats accumulator ----
__global__ __launch_bounds__(256) void k_zero(float* __restrict__ ACC) {
    ACC[threadIdx.x] = 0.f;
    ACC[256 + threadIdx.x] = 0.f;
}

// ---- cast x fp32->bf16 into C cols [0,64); accumulate per-channel sum/sumsq ----
__global__ __launch_bounds__(256) void k_cast(const float* __restrict__ x,
                                              unsigned short* __restrict__ C,
                                              float* __restrict__ ACC) {
    const int t = threadIdx.x;
    const int wv = t >> 6, lane = t & 63;
    const int v = blockIdx.x * 64 + (t >> 2);
    const int c0 = (t & 3) * 16;
    float f[16];
    const bool valid = v < NV;
    if (valid) {
        const float4* p = (const float4*)(x + (size_t)v * 64 + c0);
#pragma unroll
        for (int i = 0; i < 4; ++i) {
            float4 q = p[i];
            f[i * 4 + 0] = q.x; f[i * 4 + 1] = q.y; f[i * 4 + 2] = q.z; f[i * 4 + 3] = q.w;
        }
        unsigned int o[8];
#pragma unroll
        for (int i = 0; i < 8; ++i)
            o[i] = ((unsigned int)f2bf(f[2 * i])) | (((unsigned int)f2bf(f[2 * i + 1])) << 16);
        uint4* dst = (uint4*)(C + (size_t)v * 256 + c0);
        dst[0] = uint4{o[0], o[1], o[2], o[3]};
        dst[1] = uint4{o[4], o[5], o[6], o[7]};
    } else {
#pragma unroll
        for (int i = 0; i < 16; ++i) f[i] = 0.f;
    }
    float s[16], s2[16];
#pragma unroll
    for (int i = 0; i < 16; ++i) { s[i] = f[i]; s2[i] = f[i] * f[i]; }
#pragma unroll
    for (int mask = 4; mask <= 32; mask <<= 1) {
#pragma unroll
        for (int i = 0; i < 16; ++i) {
            s[i]  += __shfl_xor(s[i],  mask);
            s2[i] += __shfl_xor(s2[i], mask);
        }
    }
    __shared__ float red[4 * 128];
    if ((lane >> 2) == 0) {
        int cb = (lane & 3) * 16;
#pragma unroll
        for (int i = 0; i < 16; ++i) {
            red[wv * 128 + cb + i]      = s[i];
            red[wv * 128 + 64 + cb + i] = s2[i];
        }
    }
    __syncthreads();
    if (t < 128) {
        float v4 = red[t] + red[128 + t] + red[256 + t] + red[384 + t];
        int c = t & 63, which = t >> 6;
        atomicAdd(&ACC[which * 256 + c], v4);
    }
}

// ---- transpose all four W [7cin,64] fp32 -> WT [64,7cin] bf16 ----
__global__ __launch_bounds__(256) void k_wt_all(const float* __restrict__ W1,
                                                const float* __restrict__ W2,
                                                const float* __restrict__ W3,
                                                const float* __restrict__ W4,
                                                unsigned short* __restrict__ WT) {
    int j = blockIdx.x * 256 + threadIdx.x;
    if (j >= 286720) return;
    const float* W; int jj, K7;
    if (j < 28672)       { W = W1; jj = j;          K7 = 448;  }
    else if (j < 86016)  { W = W2; jj = j - 28672;  K7 = 896;  }
    else if (j < 172032) { W = W3; jj = j - 86016;  K7 = 1344; }
    else                 { W = W4; jj = j - 172032; K7 = 1792; }
    int n = jj / K7, k = jj - n * K7;
    WT[j] = f2bf(W[(size_t)k * 64 + n]);
}

// ---- per-layer BN+LeakyReLU applied once per element: C cols[0,CIN) -> Y[N,CIN] bf16 ----
template<int CIN>
__global__ __launch_bounds__(256) void k_apply(const unsigned short* __restrict__ C,
                                               const float* __restrict__ ACC,
                                               const float* __restrict__ g,
                                               const float* __restrict__ bglob,
                                               unsigned short* __restrict__ Y) {
    __shared__ float ssc[CIN], ssh[CIN];
    const int t = threadIdx.x;
    if (t < CIN) {
        float s = ACC[t], s2 = ACC[256 + t];
        float mu = s * (1.0f / NV);
        float var = fmaf(-mu, mu, s2 * (1.0f / NV));
        float sc = g[t] * rsqrtf(var + EPSV);
        ssc[t] = sc;
        ssh[t] = bglob[t] - mu * sc;
    }
    __syncthreads();
    constexpr int C8 = CIN / 8;
    int e = blockIdx.x * 256 + t;
    if (e >= NV * C8) return;
    int v = e / C8, c8 = e - v * C8;
    int ch = c8 * 8;
    uint4 u = *(const uint4*)(C + (size_t)v * 256 + ch);
    float f[8];
    bf2x(u.x, f[0], f[1]); bf2x(u.y, f[2], f[3]);
    bf2x(u.z, f[4], f[5]); bf2x(u.w, f[6], f[7]);
    unsigned int o[4];
#pragma unroll
    for (int jj = 0; jj < 4; ++jj) {
        float y0 = fmaf(f[2 * jj],     ssc[ch + 2 * jj],     ssh[ch + 2 * jj]);
        float y1 = fmaf(f[2 * jj + 1], ssc[ch + 2 * jj + 1], ssh[ch + 2 * jj + 1]);
        y0 = fmaxf(y0, 0.2f * y0);
        y1 = fmaxf(y1, 0.2f * y1);
        o[jj] = pack2(y0, y1);
    }
    *(uint4*)(Y + (size_t)v * CIN + ch) = uint4{o[0], o[1], o[2], o[3]};
}

// ---- gather-GEMM: A-frags global->VGPR (gather IS the A load), B k64-chunks in LDS ----
// M=128/block (32/wave), 256 threads. Prefetch A+W for chunk c+1 before chunk c's barriers.
template<int CIN, int GRP, bool FINAL>
__global__ __launch_bounds__(256, 4) void k_gg(const unsigned short* __restrict__ Y,
                                               const int* __restrict__ neigh,
                                               const unsigned short* __restrict__ WT,
                                               const float* __restrict__ wb,
                                               float* __restrict__ ACC,
                                               unsigned short* __restrict__ Cout,
                                               float* __restrict__ Fout) {
    constexpr int KB = CIN / 64;       // k64 chunks per neighbor row
    constexpr int NC = 7 * KB;         // total chunks (7/14/21/28)
    constexpr int K7 = 7 * CIN;

    __shared__ int sIdx[896];
    __shared__ unsigned short sW[64 * 72];   // one k64 B chunk: 64 n-rows x 64 k, +8 pad

    const int t = threadIdx.x;
    const int v0 = blockIdx.x * 128;

    for (int q = t; q < 896; q += 256) {
        int gi = v0 * 7 + q;
        sIdx[q] = (gi < NV * 7) ? neigh[gi] : 0;
    }
    __syncthreads();

    const int wv = t >> 6, lane = t & 63;
    const int m = lane & 15, quad = lane >> 4;
    const int wrow = t >> 2, wq = t & 3;     // W staging: 4 thr/row, 32B each

    // byte offsets of this lane's two gather rows (per neighbor slot)
    unsigned int off0[7], off1[7];
#pragma unroll
    for (int r = 0; r < 7; ++r) {
        off0[r] = (unsigned)sIdx[(wv * 32 + m) * 7 + r] * (CIN * 2u);
        off1[r] = (unsigned)sIdx[(wv * 32 + 16 + m) * 7 + r] * (CIN * 2u);
    }
    const char* Yb = (const char*)Y;

    f32x4 acc[2][4];
#pragma unroll
    for (int i = 0; i < 2; ++i)
#pragma unroll
        for (int j = 0; j < 4; ++j) acc[i][j] = f32x4{0.f, 0.f, 0.f, 0.f};

    // A load: one k64 chunk = two k32 frags per row, direct in MFMA layout
    auto ldA = [&](int c, uint4* A0, uint4* A1) {
        int r = c / KB, kc = c % KB;               // c is compile-time (full unroll)
        const char* p0 = Yb + off0[r] + kc * 128 + quad * 16;
        A0[0] = *(const uint4*)p0;
        A0[1] = *(const uint4*)(p0 + 64);
        const char* p1 = Yb + off1[r] + kc * 128 + quad * 16;
        A1[0] = *(const uint4*)p1;
        A1[1] = *(const uint4*)(p1 + 64);
    };
    auto ldW = [&](int c, uint4& W0, uint4& W1) {
        const unsigned short* src = WT + (size_t)wrow * K7 + c * 64 + wq * 16;
        W0 = *(const uint4*)src;
        W1 = *(const uint4*)(src + 8);
    };

    uint4 a0[2], a1[2], w0, w1;
    ldA(0, a0, a1);
    ldW(0, w0, w1);

#pragma unroll
    for (int c = 0; c < NC; ++c) {
        uint4 na0[2], na1[2], nw0, nw1;
        if (c + 1 < NC) { ldA(c + 1, na0, na1); ldW(c + 1, nw0, nw1); }  // in flight over barriers
        *(uint4*)(sW + wrow * 72 + wq * 16)     = w0;
        *(uint4*)(sW + wrow * 72 + wq * 16 + 8) = w1;
        __syncthreads();
#pragma unroll
        for (int s = 0; s < 2; ++s) {
            union { uint4 u; short8 s8; } ua, ub;
            ua.u = a0[s]; ub.u = a1[s];
#pragma unroll
            for (int ct = 0; ct < 4; ++ct) {
                short8 bf = *(const short8*)(sW + (ct * 16 + m) * 72 + s * 32 + quad * 8);
                acc[0][ct] = __builtin_amdgcn_mfma_f32_16x16x32_bf16(ua.s8, bf, acc[0][ct], 0, 0, 0);
                acc[1][ct] = __builtin_amdgcn_mfma_f32_16x16x32_bf16(ub.s8, bf, acc[1][ct], 0, 0, 0);
            }
        }
        __syncthreads();
        if (c + 1 < NC) {
            a0[0] = na0[0]; a0[1] = na0[1];
            a1[0] = na1[0]; a1[1] = na1[1];
            w0 = nw0; w1 = nw1;
        }
    }

    // epilogue: bias, write, per-channel stats of the produced 64-col group
    float bsum[4]  = {0.f, 0.f, 0.f, 0.f};
    float b2sum[4] = {0.f, 0.f, 0.f, 0.f};
#pragma unroll
    for (int mt = 0; mt < 2; ++mt) {
#pragma unroll
        for (int ct = 0; ct < 4; ++ct) {
            int col = ct * 16 + m;
            float bv = wb[col];
#pragma unroll
            for (int j = 0; j < 4; ++j) {
                int vr = v0 + wv * 32 + mt * 16 + quad * 4 + j;
                float val = acc[mt][ct][j] + bv;
                if (vr < NV) {
                    if (FINAL) {
                        Fout[(size_t)vr * 64 + col] = val;
                    } else {
                        Cout[(size_t)vr * 256 + GRP * 64 + col] = f2bf(val);
                        bsum[ct] += val; b2sum[ct] += val * val;
                    }
                }
            }
        }
    }
    if (!FINAL) {
#pragma unroll
        for (int ct = 0; ct < 4; ++ct) {   // reduce over quads
            bsum[ct]  += __shfl_xor(bsum[ct], 16);
            bsum[ct]  += __shfl_xor(bsum[ct], 32);
            b2sum[ct] += __shfl_xor(b2sum[ct], 16);
            b2sum[ct] += __shfl_xor(b2sum[ct], 32);
        }
        float* red = (float*)sW;   // sW dead after last barrier
        __syncthreads();
        if (quad == 0) {
#pragma unroll
            for (int ct = 0; ct < 4; ++ct) {
                red[wv * 128 + ct * 16 + m]       = bsum[ct];
                red[512 + wv * 128 + ct * 16 + m] = b2sum[ct];
            }
        }
        __syncthreads();
        if (t < 128) {
            int c = t & 63, which = t >> 6;
            float s = red[which * 512 + c] + red[which * 512 + 128 + c] +
                      red[which * 512 + 256 + c] + red[which * 512 + 384 + c];
            atomicAdd(&ACC[which * 256 + GRP * 64 + c], s);
        }
    }
}

extern "C" void kernel_launch(void* const* d_in, const int* in_sizes, int n_in,
                              void* d_out, int out_size, void* d_ws, size_t ws_size,
                              hipStream_t stream) {
    const float* x     = (const float*)d_in[0];
    const int*   neigh = (const int*)d_in[1];
    const float* G[4]  = {(const float*)d_in[2],  (const float*)d_in[6],
                          (const float*)d_in[10], (const float*)d_in[14]};
    const float* B[4]  = {(const float*)d_in[3],  (const float*)d_in[7],
                          (const float*)d_in[11], (const float*)d_in[15]};
    const float* W[4]  = {(const float*)d_in[4],  (const float*)d_in[8],
                          (const float*)d_in[12], (const float*)d_in[16]};
    const float* WB[4] = {(const float*)d_in[5],  (const float*)d_in[9],
                          (const float*)d_in[13], (const float*)d_in[17]};
    float* out = (float*)d_out;

    char* ws = (char*)d_ws;
    size_t off = 0;
    unsigned short* C  = (unsigned short*)(ws + off); off += (size_t)NV * 256 * 2;  // raw concat x|x1|x2|x3
    unsigned short* Yb = (unsigned short*)(ws + off); off += (size_t)NV * 256 * 2;  // post-BN compact rows
    unsigned short* WT = (unsigned short*)(ws + off); off += (size_t)286720 * 2;    // transposed bf16 W
    float* ACC         = (float*)(ws + off);          off += 512 * 4;               // sum[256], sumsq[256]

    k_zero<<<1, 256, 0, stream>>>(ACC);
    k_cast<<<(NV + 63) / 64, 256, 0, stream>>>(x, C, ACC);
    k_wt_all<<<(286720 + 255) / 256, 256, 0, stream>>>(W[0], W[1], W[2], W[3], WT);

    const int GG = (NV + 127) / 128;
    const int WOFF[4] = {0, 28672, 86016, 172032};
#define APPLY(CIN, LI) k_apply<CIN><<<((NV * (CIN / 8)) + 255) / 256, 256, 0, stream>>>(C, ACC, G[LI], B[LI], Yb)
    APPLY(64, 0);
    k_gg< 64, 1, false><<<GG, 256, 0, stream>>>(Yb, neigh, WT + WOFF[0], WB[0], ACC, C, nullptr);
    APPLY(128, 1);
    k_gg<128, 2, false><<<GG, 256, 0, stream>>>(Yb, neigh, WT + WOFF[1], WB[1], ACC, C, nullptr);
    APPLY(192, 2);
    k_gg<192, 3, false><<<GG, 256, 0, stream>>>(Yb, neigh, WT + WOFF[2], WB[2], ACC, C, nullptr);
    APPLY(256, 3);
    k_gg<256, 0, true ><<<GG, 256, 0, stream>>>(Yb, neigh, WT + WOFF[3], WB[3], ACC, nullptr, out);
#undef APPLY
}